// Round 3
// baseline (45.323 us; speedup 1.0000x reference)
//
#include <hip/hip_runtime.h>

#define M 128
#define BT 256

// d_ws float layout:
//   [0    .. 1023]  T tables:  T_d at ws[2^d], size 2^d, d=0..9   (sp over path nodes)
//   [1024 .. 3071]  V tables:  V_d at ws[1024 + 2^d], d=0..10     (vals over path nodes)
//   [3072 .. 3199]  sp[128]
//   [3200 .. 3327]  vals[128]
//   [3328 .. 3455]  li[128] (int)
//   [3456 .. 3583]  ri[128] (int)

__global__ void setup_kernel(const float* __restrict__ spp,
                             const float* __restrict__ vp,
                             const float* __restrict__ Lm,
                             const float* __restrict__ Rm,
                             float* __restrict__ ws) {
  __shared__ float ssp[M], svl[M];
  __shared__ int sli[M], sri[M];
  __shared__ int cur[1024], nxt[1024];
  const int t = threadIdx.x;  // 256 threads
  if (t < M) {
    ssp[t] = 1.f / (1.f + __expf(2.f - 4.f * spp[t]));
    svl[t] = vp[t & 31] * 3.f + 1.f;
  }
  {
    // one-hot column scan: threads 0..127 -> Lm rows, 128..255 -> Rm rows
    const int row = t & (M - 1);
    const float* Mt = (t < M) ? Lm : Rm;
    const float4* r4 = (const float4*)(Mt + row * M);
    int idx = 0;
#pragma unroll
    for (int j4 = 0; j4 < M / 4; ++j4) {
      const float4 v = r4[j4];
      if (v.x > 0.5f) idx = 4 * j4;
      if (v.y > 0.5f) idx = 4 * j4 + 1;
      if (v.z > 0.5f) idx = 4 * j4 + 2;
      if (v.w > 0.5f) idx = 4 * j4 + 3;
    }
    if (t < M) sli[row] = idx; else sri[row] = idx;
  }
  __syncthreads();
  if (t < M) {
    ws[3072 + t] = ssp[t];
    ws[3200 + t] = svl[t];
    ((int*)ws)[3328 + t] = sli[t];
    ((int*)ws)[3456 + t] = sri[t];
  }
  if (t == 0) cur[0] = 0;
  __syncthreads();
  int S = 1;
  for (int d = 0; d <= 10; ++d) {
    for (int i = t; i < S; i += 256) {
      const int nd = cur[i];
      ws[1024 + S + i] = svl[nd];
      if (d <= 9) ws[S + i] = ssp[nd];
      if (d < 10) { nxt[2 * i] = sli[nd]; nxt[2 * i + 1] = sri[nd]; }
    }
    __syncthreads();
    if (d < 10) {
      for (int i = t; i < 2 * S; i += 256) cur[i] = nxt[i];
      __syncthreads();
    }
    S <<= 1;
  }
}

#define SIGSTEP(dotv)                                   \
  {                                                     \
    const float sv = fmaf((dotv), hi - lo, lo);         \
    tt = 1.f / (1.f + __expf((sv - xv) * 10.f));        \
    uu = 1.f - tt;                                      \
    const float nlo = fmaf(tt, sv, uu * lo);            \
    const float nhi = fmaf(tt, hi, uu * sv);            \
    lo = nlo; hi = nhi;                                 \
  }

__launch_bounds__(BT)
__global__ void fractal10(const float* __restrict__ x,
                          const int* __restrict__ dpt,
                          float* __restrict__ out, int n,
                          const float* __restrict__ T,
                          const float* __restrict__ V10) {
  if (dpt[0] != 10) return;
  const int gid = blockIdx.x * BT + threadIdx.x;
  const float xv = (gid < n) ? x[gid] : 0.5f;

  float c[64], W[16];
  float lo = 0.f, hi = 1.f;
  float tt, uu;

  // k=1: T_0 at T[1]
  SIGSTEP(T[1]);
  c[0] = uu; c[1] = tt;
  // k=2: T_1 at T[2]
  SIGSTEP(fmaf(c[0], T[2], c[1] * T[3]));
  { const float a0 = c[0], a1 = c[1];
    c[0] = a0 * uu; c[1] = a0 * tt; c[2] = a1 * uu; c[3] = a1 * tt; }
  // k=3: T_2 at T[4]
  { const float d0 = fmaf(c[0], T[4], c[2] * T[6]);
    const float d1 = fmaf(c[1], T[5], c[3] * T[7]);
    SIGSTEP(d0 + d1); }
#pragma unroll
  for (int i = 3; i >= 0; --i) { const float v = c[i]; c[2*i+1] = v*tt; c[2*i] = v*uu; }
  // k=4: T_3 at T[8], 8 entries
  { float d0 = 0.f, d1 = 0.f, d2 = 0.f, d3 = 0.f;
#pragma unroll
    for (int i = 0; i < 8; i += 4) {
      d0 = fmaf(c[i],   T[8+i],   d0);
      d1 = fmaf(c[i+1], T[8+i+1], d1);
      d2 = fmaf(c[i+2], T[8+i+2], d2);
      d3 = fmaf(c[i+3], T[8+i+3], d3);
    }
    SIGSTEP((d0 + d1) + (d2 + d3)); }
#pragma unroll
  for (int i = 7; i >= 0; --i) { const float v = c[i]; c[2*i+1] = v*tt; c[2*i] = v*uu; }
  // k=5: T_4 at T[16], 16 entries
  { float d0 = 0.f, d1 = 0.f, d2 = 0.f, d3 = 0.f;
#pragma unroll
    for (int i = 0; i < 16; i += 4) {
      d0 = fmaf(c[i],   T[16+i],   d0);
      d1 = fmaf(c[i+1], T[16+i+1], d1);
      d2 = fmaf(c[i+2], T[16+i+2], d2);
      d3 = fmaf(c[i+3], T[16+i+3], d3);
    }
    SIGSTEP((d0 + d1) + (d2 + d3)); }
#pragma unroll
  for (int i = 15; i >= 0; --i) { const float v = c[i]; c[2*i+1] = v*tt; c[2*i] = v*uu; }
  // k=6: T_5 at T[32], 32 entries
  { float d0 = 0.f, d1 = 0.f, d2 = 0.f, d3 = 0.f;
#pragma unroll
    for (int i = 0; i < 32; i += 4) {
      d0 = fmaf(c[i],   T[32+i],   d0);
      d1 = fmaf(c[i+1], T[32+i+1], d1);
      d2 = fmaf(c[i+2], T[32+i+2], d2);
      d3 = fmaf(c[i+3], T[32+i+3], d3);
    }
    SIGSTEP((d0 + d1) + (d2 + d3)); }
#pragma unroll
  for (int i = 31; i >= 0; --i) { const float v = c[i]; c[2*i+1] = v*tt; c[2*i] = v*uu; }
  // k=7: T_6 at T[64], 64 entries — 8 accumulators
  { float d0=0.f,d1=0.f,d2=0.f,d3=0.f,d4=0.f,d5=0.f,d6=0.f,d7=0.f;
#pragma unroll
    for (int i = 0; i < 64; i += 8) {
      d0 = fmaf(c[i],   T[64+i],   d0);
      d1 = fmaf(c[i+1], T[64+i+1], d1);
      d2 = fmaf(c[i+2], T[64+i+2], d2);
      d3 = fmaf(c[i+3], T[64+i+3], d3);
      d4 = fmaf(c[i+4], T[64+i+4], d4);
      d5 = fmaf(c[i+5], T[64+i+5], d5);
      d6 = fmaf(c[i+6], T[64+i+6], d6);
      d7 = fmaf(c[i+7], T[64+i+7], d7);
    }
    SIGSTEP(((d0+d1)+(d2+d3)) + ((d4+d5)+(d6+d7))); }
  W[0] = uu; W[1] = tt;
  // k=8: T_7 at T[128], 128 entries, suffix width 2
  { float d0 = 0.f, d1 = 0.f, d2 = 0.f, d3 = 0.f;
#pragma unroll
    for (int i = 0; i < 64; i += 4) {
      d0 = fmaf(c[i],   fmaf(W[0], T[128+2*i],   W[1]*T[128+2*i+1]), d0);
      d1 = fmaf(c[i+1], fmaf(W[0], T[128+2*i+2], W[1]*T[128+2*i+3]), d1);
      d2 = fmaf(c[i+2], fmaf(W[0], T[128+2*i+4], W[1]*T[128+2*i+5]), d2);
      d3 = fmaf(c[i+3], fmaf(W[0], T[128+2*i+6], W[1]*T[128+2*i+7]), d3);
    }
    SIGSTEP((d0 + d1) + (d2 + d3)); }
#pragma unroll
  for (int i = 1; i >= 0; --i) { const float v = W[i]; W[2*i+1] = v*tt; W[2*i] = v*uu; }
  // k=9: T_8 at T[256], 256 entries, suffix width 4
  { float d0 = 0.f, d1 = 0.f, d2 = 0.f, d3 = 0.f;
#pragma unroll
    for (int i = 0; i < 64; i += 4) {
      float a0 = fmaf(W[0], T[256+4*i],    W[1]*T[256+4*i+1]);
      a0 = fmaf(W[2], T[256+4*i+2],  fmaf(W[3], T[256+4*i+3],  a0));
      float a1 = fmaf(W[0], T[256+4*i+4],  W[1]*T[256+4*i+5]);
      a1 = fmaf(W[2], T[256+4*i+6],  fmaf(W[3], T[256+4*i+7],  a1));
      float a2 = fmaf(W[0], T[256+4*i+8],  W[1]*T[256+4*i+9]);
      a2 = fmaf(W[2], T[256+4*i+10], fmaf(W[3], T[256+4*i+11], a2));
      float a3 = fmaf(W[0], T[256+4*i+12], W[1]*T[256+4*i+13]);
      a3 = fmaf(W[2], T[256+4*i+14], fmaf(W[3], T[256+4*i+15], a3));
      d0 = fmaf(c[i], a0, d0);
      d1 = fmaf(c[i+1], a1, d1);
      d2 = fmaf(c[i+2], a2, d2);
      d3 = fmaf(c[i+3], a3, d3);
    }
    SIGSTEP((d0 + d1) + (d2 + d3)); }
#pragma unroll
  for (int i = 3; i >= 0; --i) { const float v = W[i]; W[2*i+1] = v*tt; W[2*i] = v*uu; }
  // k=10: T_9 at T[512], 512 entries, suffix width 8
  { float d0 = 0.f, d1 = 0.f, d2 = 0.f, d3 = 0.f;
#pragma unroll
    for (int i = 0; i < 64; i += 4) {
#pragma unroll
      for (int q = 0; q < 4; ++q) {
        const int b = 512 + 8 * (i + q);
        float a = fmaf(W[0], T[b],   W[1]*T[b+1]);
        float bq = fmaf(W[2], T[b+2], W[3]*T[b+3]);
        float cq = fmaf(W[4], T[b+4], W[5]*T[b+5]);
        float dq = fmaf(W[6], T[b+6], W[7]*T[b+7]);
        a = (a + bq) + (cq + dq);
        if (q == 0) d0 = fmaf(c[i], a, d0);
        else if (q == 1) d1 = fmaf(c[i+1], a, d1);
        else if (q == 2) d2 = fmaf(c[i+2], a, d2);
        else d3 = fmaf(c[i+3], a, d3);
      }
    }
    SIGSTEP((d0 + d1) + (d2 + d3)); }
#pragma unroll
  for (int i = 7; i >= 0; --i) { const float v = W[i]; W[2*i+1] = v*tt; W[2*i] = v*uu; }
  // output: V_10 at V10[0..1023], suffix width 16
  float outv;
  { float d0 = 0.f, d1 = 0.f, d2 = 0.f, d3 = 0.f;
#pragma unroll
    for (int i = 0; i < 64; i += 4) {
#pragma unroll
      for (int q = 0; q < 4; ++q) {
        const int b = 16 * (i + q);
        float a0 = fmaf(W[0],  V10[b],    W[1]*V10[b+1]);
        float a1 = fmaf(W[2],  V10[b+2],  W[3]*V10[b+3]);
        float a2 = fmaf(W[4],  V10[b+4],  W[5]*V10[b+5]);
        float a3 = fmaf(W[6],  V10[b+6],  W[7]*V10[b+7]);
        float a4 = fmaf(W[8],  V10[b+8],  W[9]*V10[b+9]);
        float a5 = fmaf(W[10], V10[b+10], W[11]*V10[b+11]);
        float a6 = fmaf(W[12], V10[b+12], W[13]*V10[b+13]);
        float a7 = fmaf(W[14], V10[b+14], W[15]*V10[b+15]);
        const float a = ((a0+a1)+(a2+a3)) + ((a4+a5)+(a6+a7));
        if (q == 0) d0 = fmaf(c[i], a, d0);
        else if (q == 1) d1 = fmaf(c[i+1], a, d1);
        else if (q == 2) d2 = fmaf(c[i+2], a, d2);
        else d3 = fmaf(c[i+3], a, d3);
      }
    }
    outv = (d0 + d1) + (d2 + d3); }

  if (gid < n) out[gid] = outv;
}

// Generic-depth fallback (never taken when depth==10; correctness only).
__launch_bounds__(64)
__global__ void fractal_generic(const float* __restrict__ x,
                                const int* __restrict__ dpt,
                                float* __restrict__ out, int n,
                                const float* __restrict__ ws) {
  const int depth = dpt[0];
  if (depth == 10) return;
  const float* sp = ws + 3072;
  const float* vals = ws + 3200;
  const int* li = (const int*)ws + 3328;
  const int* ri = (const int*)ws + 3456;
  for (int gid = blockIdx.x * 64 + threadIdx.x; gid < n; gid += gridDim.x * 64) {
    const float xv = x[gid];
    float w0[M], w1[M];
    for (int j = 0; j < M; ++j) w0[j] = 0.f;
    w0[0] = 1.f;
    float lo = 0.f, hi = 1.f;
    float* wc = w0; float* wn = w1;
    for (int k = 0; k < depth; ++k) {
      float dot = 0.f;
      for (int j = 0; j < M; ++j) dot += wc[j] * sp[j];
      const float sv = lo + dot * (hi - lo);
      const float t = 1.f / (1.f + __expf((sv - xv) * 10.f));
      const float u = 1.f - t;
      for (int j = 0; j < M; ++j) wn[j] = 0.f;
      for (int j = 0; j < M; ++j) {
        const float v = wc[j];
        wn[li[j]] += u * v;
        wn[ri[j]] += t * v;
      }
      const float nlo = u * lo + t * sv;
      const float nhi = u * sv + t * hi;
      lo = nlo; hi = nhi;
      float* tmp = wc; wc = wn; wn = tmp;
    }
    float acc = 0.f;
    for (int j = 0; j < M; ++j) acc += wc[j] * vals[j];
    out[gid] = acc;
  }
}

extern "C" void kernel_launch(void* const* d_in, const int* in_sizes, int n_in,
                              void* d_out, int out_size, void* d_ws, size_t ws_size,
                              hipStream_t stream) {
  const float* x   = (const float*)d_in[0];
  const float* spp = (const float*)d_in[1];
  const float* vp  = (const float*)d_in[2];
  const float* Lm  = (const float*)d_in[3];
  const float* Rm  = (const float*)d_in[4];
  const int* dpt   = (const int*)d_in[5];
  float* out = (float*)d_out;
  float* ws = (float*)d_ws;
  const int n = in_sizes[0];

  hipLaunchKernelGGL(setup_kernel, dim3(1), dim3(256), 0, stream, spp, vp, Lm, Rm, ws);
  const int blocks = (n + BT - 1) / BT;
  hipLaunchKernelGGL(fractal10, dim3(blocks), dim3(BT), 0, stream,
                     x, dpt, out, n, (const float*)ws, (const float*)(ws + 2048));
  hipLaunchKernelGGL(fractal_generic, dim3(128), dim3(64), 0, stream, x, dpt, out, n,
                     (const float*)ws);
}

// Round 5
// 20.278 us; speedup vs baseline: 2.2351x; 2.2351x over previous
//
#include <hip/hip_runtime.h>

#define M 128
#define BT 64

typedef _Float16 half8 __attribute__((ext_vector_type(8)));
typedef __fp16 fp16x2 __attribute__((ext_vector_type(2)));
typedef float f32x4 __attribute__((ext_vector_type(4)));

// d_ws float layout:
//   [0    .. 1023]  T tables:  T_d at ws[2^d], size 2^d, d=0..9   (sp over path nodes)
//   [1024 .. 3071]  V tables:  V_d at ws[1024 + 2^d], d=0..10
//   [3072 .. 3583]  sp/vals/li/ri for generic fallback
//   [4096 .. 5119]  A-fragment buffer: 4 frags x 64 lanes x 16B (f16, MFMA layout)
//
// A-matrix (Bt, 32x64): Bt[prow][i] :=
//   prow 0      -> T6[i]            = ws[64+i]
//   prow 1..2   -> T7[2i+(prow-1)]  = ws[128+...]
//   prow 3..6   -> T8[4i+(prow-3)]  = ws[256+...]
//   prow 7..14  -> T9[8i+(prow-7)]  = ws[512+...]
//   prow 15..30 -> V10[16i+(prow-15)] = ws[2048+...]
//   prow 31     -> 0

__global__ void setup_kernel(const float* __restrict__ spp,
                             const float* __restrict__ vp,
                             const float* __restrict__ Lm,
                             const float* __restrict__ Rm,
                             float* __restrict__ ws) {
  __shared__ float ssp[M], svl[M];
  __shared__ int sli[M], sri[M];
  __shared__ int cur[1024], nxt[1024];
  const int t = threadIdx.x;  // 256 threads
  if (t < M) {
    ssp[t] = 1.f / (1.f + __expf(2.f - 4.f * spp[t]));
    svl[t] = vp[t & 31] * 3.f + 1.f;
  }
  {
    const int row = t & (M - 1);
    const float* Mt = (t < M) ? Lm : Rm;
    const float4* r4 = (const float4*)(Mt + row * M);
    int idx = 0;
#pragma unroll
    for (int j4 = 0; j4 < M / 4; ++j4) {
      const float4 v = r4[j4];
      if (v.x > 0.5f) idx = 4 * j4;
      if (v.y > 0.5f) idx = 4 * j4 + 1;
      if (v.z > 0.5f) idx = 4 * j4 + 2;
      if (v.w > 0.5f) idx = 4 * j4 + 3;
    }
    if (t < M) sli[row] = idx; else sri[row] = idx;
  }
  __syncthreads();
  if (t < M) {
    ws[3072 + t] = ssp[t];
    ws[3200 + t] = svl[t];
    ((int*)ws)[3328 + t] = sli[t];
    ((int*)ws)[3456 + t] = sri[t];
  }
  if (t == 0) cur[0] = 0;
  __syncthreads();
  int S = 1;
  for (int d = 0; d <= 10; ++d) {
    for (int i = t; i < S; i += 256) {
      const int nd = cur[i];
      ws[1024 + S + i] = svl[nd];
      if (d <= 9) ws[S + i] = ssp[nd];
      if (d < 10) { nxt[2 * i] = sli[nd]; nxt[2 * i + 1] = sri[nd]; }
    }
    __syncthreads();
    if (d < 10) {
      for (int i = t; i < 2 * S; i += 256) cur[i] = nxt[i];
      __syncthreads();
    }
    S <<= 1;
  }
  __syncthreads();
  // Build pre-packed f16 A-fragments. Element e of a lane's 16B frag holds
  // k-local kl = (e<4) ? 4g+e : 16+4g+(e-4); i = ks*32 + kl. Same convention
  // is used for the B operand in the main kernel, so the HW k-slot mapping
  // cancels regardless of its exact (g,e)->k bijection.
  unsigned* fbout = (unsigned*)(ws + 4096);
  for (int d = t; d < 1024; d += 256) {
    const int dw = d & 3;
    const int lane = (d >> 2) & 63;
    const int rt = d >> 9;
    const int ks = (d >> 8) & 1;
    const int m = lane & 15, gg = lane >> 4;
    const int prow = rt * 16 + m;
    float v[2];
#pragma unroll
    for (int h = 0; h < 2; ++h) {
      const int e = 2 * dw + h;
      const int kl = (e < 4) ? (4 * gg + e) : (16 + 4 * gg + (e - 4));
      const int i = ks * 32 + kl;
      float val;
      if (prow == 0) val = ws[64 + i];
      else if (prow < 3) val = ws[128 + 2 * i + (prow - 1)];
      else if (prow < 7) val = ws[256 + 4 * i + (prow - 3)];
      else if (prow < 15) val = ws[512 + 8 * i + (prow - 7)];
      else if (prow < 31) val = ws[2048 + 16 * i + (prow - 15)];
      else val = 0.f;
      v[h] = val;
    }
    union { fp16x2 h; unsigned u; } pu;
    pu.h = __builtin_amdgcn_cvt_pkrtz(v[0], v[1]);
    fbout[d] = pu.u;
  }
}

#define PSTEP(S)                                                              \
  {                                                                           \
    float dot = 0.f;                                                          \
    _Pragma("unroll") for (int i = 0; i < (S); ++i)                           \
        dot = fmaf(c[i], sT[(S) + i], dot);                                   \
    const float sv = fmaf(dot, hi - lo, lo);                                  \
    tt = 1.f / (1.f + __expf((sv - xv) * 10.f));                              \
    uu = 1.f - tt;                                                            \
    const float nlo = fmaf(tt, sv, uu * lo);                                  \
    const float nhi = fmaf(tt, hi, uu * sv);                                  \
    lo = nlo; hi = nhi;                                                       \
    _Pragma("unroll") for (int i = (S)-1; i >= 0; --i) {                      \
      const float v = c[i];                                                   \
      c[2 * i + 1] = v * tt;                                                  \
      c[2 * i] = v * uu;                                                      \
    }                                                                         \
  }

#define SIGSTEP(dotv)                                   \
  {                                                     \
    const float sv = fmaf((dotv), hi - lo, lo);         \
    tt = 1.f / (1.f + __expf((sv - xv) * 10.f));        \
    uu = 1.f - tt;                                      \
    const float nlo = fmaf(tt, sv, uu * lo);            \
    const float nhi = fmaf(tt, hi, uu * sv);            \
    lo = nlo; hi = nhi;                                 \
  }

__launch_bounds__(BT)
__global__ void fractal10(const float* __restrict__ x,
                          const int* __restrict__ dpt,
                          float* __restrict__ out, int n,
                          const float* __restrict__ ws) {
  if (dpt[0] != 10) return;
  __shared__ float sT[64];
  __shared__ __align__(16) float sbuf[64 * 32];  // 8KB: c(f16) then P(f32), per point 128B
  const int l = threadIdx.x;
  const int gid = blockIdx.x * BT + l;

  sT[l] = ws[l];
  const float4* fb = (const float4*)(ws + 4096);
  union f4h8 { float4 f; half8 h; };
  f4h8 A00, A01, A10, A11;
  A00.f = fb[0 * 64 + l];   // rt0 ks0
  A01.f = fb[1 * 64 + l];   // rt0 ks1
  A10.f = fb[2 * 64 + l];   // rt1 ks0
  A11.f = fb[3 * 64 + l];   // rt1 ks1
  const float xv = (gid < n) ? x[gid] : 0.5f;
  __syncthreads();

  float c[64];
  float lo = 0.f, hi = 1.f, tt, uu;
  c[0] = 1.f;
  PSTEP(1) PSTEP(2) PSTEP(4) PSTEP(8) PSTEP(16) PSTEP(32)

  // pack c -> f16, write [point][chunk] with XOR-16B swizzle
  {
    char* cb = (char*)sbuf + l * 128;
#pragma unroll
    for (int q = 0; q < 8; ++q) {
      const int k0 = (q >> 2) * 32 + (q & 3) * 4;
      union { fp16x2 h2[4]; float4 f4; } u;
      u.h2[0] = __builtin_amdgcn_cvt_pkrtz(c[k0], c[k0 + 1]);
      u.h2[1] = __builtin_amdgcn_cvt_pkrtz(c[k0 + 2], c[k0 + 3]);
      u.h2[2] = __builtin_amdgcn_cvt_pkrtz(c[k0 + 16], c[k0 + 17]);
      u.h2[3] = __builtin_amdgcn_cvt_pkrtz(c[k0 + 18], c[k0 + 19]);
      *(float4*)(cb + ((q ^ (l & 7)) * 16)) = u.f4;
    }
  }
  __syncthreads();

  // read B fragments (transposed c)
  half8 bf[2][4];
  const int col = l & 15, g = l >> 4;
#pragma unroll
  for (int ct = 0; ct < 4; ++ct) {
    const int p = 16 * ct + col;
    const char* pb = (const char*)sbuf + p * 128;
#pragma unroll
    for (int ks = 0; ks < 2; ++ks) {
      const int q = ks * 4 + g;
      bf[ks][ct] = *(const half8*)(pb + ((q ^ (p & 7)) * 16));
    }
  }
  __syncthreads();

  // P[32 x 64pts] = Bt(32x64) x C(64x64)
  f32x4 acc[2][4];
#pragma unroll
  for (int rt = 0; rt < 2; ++rt)
#pragma unroll
    for (int ct = 0; ct < 4; ++ct) acc[rt][ct] = f32x4{0.f, 0.f, 0.f, 0.f};
#pragma unroll
  for (int ct = 0; ct < 4; ++ct) {
    acc[0][ct] = __builtin_amdgcn_mfma_f32_16x16x32_f16(A00.h, bf[0][ct], acc[0][ct], 0, 0, 0);
    acc[0][ct] = __builtin_amdgcn_mfma_f32_16x16x32_f16(A01.h, bf[1][ct], acc[0][ct], 0, 0, 0);
    acc[1][ct] = __builtin_amdgcn_mfma_f32_16x16x32_f16(A10.h, bf[0][ct], acc[1][ct], 0, 0, 0);
    acc[1][ct] = __builtin_amdgcn_mfma_f32_16x16x32_f16(A11.h, bf[1][ct], acc[1][ct], 0, 0, 0);
  }

  // scatter P back: D layout col=lane&15, row=(lane>>4)*4+reg (m89-verified)
#pragma unroll
  for (int rt = 0; rt < 2; ++rt)
#pragma unroll
    for (int ct = 0; ct < 4; ++ct) {
      const int p = 16 * ct + col;
      const int rb = rt * 4 + g;
      *(f32x4*)((char*)sbuf + p * 128 + ((rb ^ (p & 7)) * 16)) = acc[rt][ct];
    }
  __syncthreads();
  float4 P[8];
#pragma unroll
  for (int j = 0; j < 8; ++j)
    P[j] = *(const float4*)((const char*)sbuf + l * 128 + ((j ^ (l & 7)) * 16));

  // sequential tail on P: rows 0 | 1..2 | 3..6 | 7..14 | 15..30
  SIGSTEP(P[0].x);
  const float w20 = uu, w21 = tt;
  SIGSTEP(fmaf(w20, P[0].y, w21 * P[0].z));
  float W4[4] = {w20 * uu, w20 * tt, w21 * uu, w21 * tt};
  SIGSTEP(fmaf(W4[0], P[0].w, fmaf(W4[1], P[1].x, fmaf(W4[2], P[1].y, W4[3] * P[1].z))));
  float W8[8];
#pragma unroll
  for (int s = 3; s >= 0; --s) { W8[2 * s + 1] = W4[s] * tt; W8[2 * s] = W4[s] * uu; }
  {
    float d0 = fmaf(W8[0], P[1].w, W8[1] * P[2].x);
    float d1 = fmaf(W8[2], P[2].y, W8[3] * P[2].z);
    float d2 = fmaf(W8[4], P[2].w, W8[5] * P[3].x);
    float d3 = fmaf(W8[6], P[3].y, W8[7] * P[3].z);
    SIGSTEP((d0 + d1) + (d2 + d3));
  }
  float W16[16];
#pragma unroll
  for (int s = 7; s >= 0; --s) { W16[2 * s + 1] = W8[s] * tt; W16[2 * s] = W8[s] * uu; }
  float outv;
  {
    float d0 = fmaf(W16[0], P[3].w, W16[1] * P[4].x);
    d0 = fmaf(W16[2], P[4].y, d0); d0 = fmaf(W16[3], P[4].z, d0);
    float d1 = fmaf(W16[4], P[4].w, W16[5] * P[5].x);
    d1 = fmaf(W16[6], P[5].y, d1); d1 = fmaf(W16[7], P[5].z, d1);
    float d2 = fmaf(W16[8], P[5].w, W16[9] * P[6].x);
    d2 = fmaf(W16[10], P[6].y, d2); d2 = fmaf(W16[11], P[6].z, d2);
    float d3 = fmaf(W16[12], P[6].w, W16[13] * P[7].x);
    d3 = fmaf(W16[14], P[7].y, d3); d3 = fmaf(W16[15], P[7].z, d3);
    outv = (d0 + d1) + (d2 + d3);
  }
  if (gid < n) out[gid] = outv;
}

// Generic-depth fallback (never taken when depth==10; correctness only).
__launch_bounds__(64)
__global__ void fractal_generic(const float* __restrict__ x,
                                const int* __restrict__ dpt,
                                float* __restrict__ out, int n,
                                const float* __restrict__ ws) {
  const int depth = dpt[0];
  if (depth == 10) return;
  const float* sp = ws + 3072;
  const float* vals = ws + 3200;
  const int* li = (const int*)ws + 3328;
  const int* ri = (const int*)ws + 3456;
  for (int gid = blockIdx.x * 64 + threadIdx.x; gid < n; gid += gridDim.x * 64) {
    const float xv = x[gid];
    float w0[M], w1[M];
    for (int j = 0; j < M; ++j) w0[j] = 0.f;
    w0[0] = 1.f;
    float lo = 0.f, hi = 1.f;
    float* wc = w0; float* wn = w1;
    for (int k = 0; k < depth; ++k) {
      float dot = 0.f;
      for (int j = 0; j < M; ++j) dot += wc[j] * sp[j];
      const float sv = lo + dot * (hi - lo);
      const float t = 1.f / (1.f + __expf((sv - xv) * 10.f));
      const float u = 1.f - t;
      for (int j = 0; j < M; ++j) wn[j] = 0.f;
      for (int j = 0; j < M; ++j) {
        const float v = wc[j];
        wn[li[j]] += u * v;
        wn[ri[j]] += t * v;
      }
      const float nlo = u * lo + t * sv;
      const float nhi = u * sv + t * hi;
      lo = nlo; hi = nhi;
      float* tmp = wc; wc = wn; wn = tmp;
    }
    float acc = 0.f;
    for (int j = 0; j < M; ++j) acc += wc[j] * vals[j];
    out[gid] = acc;
  }
}

extern "C" void kernel_launch(void* const* d_in, const int* in_sizes, int n_in,
                              void* d_out, int out_size, void* d_ws, size_t ws_size,
                              hipStream_t stream) {
  const float* x   = (const float*)d_in[0];
  const float* spp = (const float*)d_in[1];
  const float* vp  = (const float*)d_in[2];
  const float* Lm  = (const float*)d_in[3];
  const float* Rm  = (const float*)d_in[4];
  const int* dpt   = (const int*)d_in[5];
  float* out = (float*)d_out;
  float* ws = (float*)d_ws;
  const int n = in_sizes[0];

  hipLaunchKernelGGL(setup_kernel, dim3(1), dim3(256), 0, stream, spp, vp, Lm, Rm, ws);
  const int blocks = (n + BT - 1) / BT;
  hipLaunchKernelGGL(fractal10, dim3(blocks), dim3(BT), 0, stream,
                     x, dpt, out, n, (const float*)ws);
  hipLaunchKernelGGL(fractal_generic, dim3(128), dim3(64), 0, stream, x, dpt, out, n,
                     (const float*)ws);
}

// Round 6
// 19.731 us; speedup vs baseline: 2.2971x; 1.0277x over previous
//
#include <hip/hip_runtime.h>

#define M 128
#define BT 64

typedef _Float16 half8 __attribute__((ext_vector_type(8)));
typedef __fp16 fp16x2 __attribute__((ext_vector_type(2)));
typedef float f32x4 __attribute__((ext_vector_type(4)));

// d_ws float layout (only what consumers actually read):
//   [0    .. 63]    prefix T tables: T_d at ws[2^d], size 2^d, d=0..5 (ws[0] = 0)
//   [3072 .. 3583]  sp/vals/li/ri for generic fallback
//   [4096 .. 5119]  A-fragment buffer: 4 frags x 64 lanes x 16B (f16, MFMA layout)
//
// A-matrix (Bt, 32x64): Bt[prow][i] :=
//   prow 0      -> T6[i]
//   prow 1..2   -> T7[2i+(prow-1)]
//   prow 3..6   -> T8[4i+(prow-3)]
//   prow 7..14  -> T9[8i+(prow-7)]
//   prow 15..30 -> V10[16i+(prow-15)]
//   prow 31     -> 0

__global__ void setup_kernel(const float* __restrict__ spp,
                             const float* __restrict__ vp,
                             const float* __restrict__ Lm,
                             const float* __restrict__ Rm,
                             float* __restrict__ ws) {
  __shared__ float ssp[M], svl[M];
  __shared__ int sli[M], sri[M];
  __shared__ float sT[1024];   // T_d at sT[2^d + i], d=0..9
  __shared__ float sV10[1024]; // V10[i]
  __shared__ int cur[1024], nxt[1024];
  const int t = threadIdx.x;  // 256 threads
  if (t < M) {
    ssp[t] = 1.f / (1.f + __expf(2.f - 4.f * spp[t]));
    svl[t] = vp[t & 31] * 3.f + 1.f;
  }
  {
    // one-hot column scan: threads 0..127 -> Lm rows, 128..255 -> Rm rows
    const int row = t & (M - 1);
    const float* Mt = (t < M) ? Lm : Rm;
    const float4* r4 = (const float4*)(Mt + row * M);
    int idx = 0;
#pragma unroll
    for (int j4 = 0; j4 < M / 4; ++j4) {
      const float4 v = r4[j4];
      if (v.x > 0.5f) idx = 4 * j4;
      if (v.y > 0.5f) idx = 4 * j4 + 1;
      if (v.z > 0.5f) idx = 4 * j4 + 2;
      if (v.w > 0.5f) idx = 4 * j4 + 3;
    }
    if (t < M) sli[row] = idx; else sri[row] = idx;
  }
  if (t == 0) { cur[0] = 0; sT[0] = 0.f; }
  __syncthreads();
  if (t < M) {
    ws[3072 + t] = ssp[t];
    ws[3200 + t] = svl[t];
    ((int*)ws)[3328 + t] = sli[t];
    ((int*)ws)[3456 + t] = sri[t];
  }
  // pointer-chase table build, fully in LDS
  int S = 1;
  for (int d = 0; d <= 10; ++d) {
    for (int i = t; i < S; i += 256) {
      const int nd = cur[i];
      if (d <= 9) sT[S + i] = ssp[nd];
      else sV10[i] = svl[nd];
      if (d < 10) { nxt[2 * i] = sli[nd]; nxt[2 * i + 1] = sri[nd]; }
    }
    __syncthreads();
    if (d < 10) {
      for (int i = t; i < 2 * S; i += 256) cur[i] = nxt[i];
      __syncthreads();
    }
    S <<= 1;
  }
  // Build pre-packed f16 A-fragments from LDS. Element e of a lane's 16B frag
  // holds k-local kl = (e<4) ? 4g+e : 16+4g+(e-4); i = ks*32 + kl. The same
  // convention packs the B operand in fractal10, so the HW k-slot mapping
  // cancels regardless of its exact (g,e)->k bijection.
  unsigned* fbout = (unsigned*)(ws + 4096);
  for (int d = t; d < 1024; d += 256) {
    const int dw = d & 3;
    const int lane = (d >> 2) & 63;
    const int rt = d >> 9;
    const int ks = (d >> 8) & 1;
    const int m = lane & 15, gg = lane >> 4;
    const int prow = rt * 16 + m;
    float v[2];
#pragma unroll
    for (int h = 0; h < 2; ++h) {
      const int e = 2 * dw + h;
      const int kl = (e < 4) ? (4 * gg + e) : (16 + 4 * gg + (e - 4));
      const int i = ks * 32 + kl;
      float val;
      if (prow == 0) val = sT[64 + i];
      else if (prow < 3) val = sT[128 + 2 * i + (prow - 1)];
      else if (prow < 7) val = sT[256 + 4 * i + (prow - 3)];
      else if (prow < 15) val = sT[512 + 8 * i + (prow - 7)];
      else if (prow < 31) val = sV10[16 * i + (prow - 15)];
      else val = 0.f;
      v[h] = val;
    }
    union { fp16x2 h; unsigned u; } pu;
    pu.h = __builtin_amdgcn_cvt_pkrtz(v[0], v[1]);
    fbout[d] = pu.u;
  }
  // prefix tables T_0..T_5 for fractal10's register phase
  if (t < 64) ws[t] = sT[t];
}

#define PSTEP(S)                                                              \
  {                                                                           \
    float dot = 0.f;                                                          \
    _Pragma("unroll") for (int i = 0; i < (S); ++i)                           \
        dot = fmaf(c[i], sT[(S) + i], dot);                                   \
    const float sv = fmaf(dot, hi - lo, lo);                                  \
    tt = 1.f / (1.f + __expf((sv - xv) * 10.f));                              \
    uu = 1.f - tt;                                                            \
    const float nlo = fmaf(tt, sv, uu * lo);                                  \
    const float nhi = fmaf(tt, hi, uu * sv);                                  \
    lo = nlo; hi = nhi;                                                       \
    _Pragma("unroll") for (int i = (S)-1; i >= 0; --i) {                      \
      const float v = c[i];                                                   \
      c[2 * i + 1] = v * tt;                                                  \
      c[2 * i] = v * uu;                                                      \
    }                                                                         \
  }

#define SIGSTEP(dotv)                                   \
  {                                                     \
    const float sv = fmaf((dotv), hi - lo, lo);         \
    tt = 1.f / (1.f + __expf((sv - xv) * 10.f));        \
    uu = 1.f - tt;                                      \
    const float nlo = fmaf(tt, sv, uu * lo);            \
    const float nhi = fmaf(tt, hi, uu * sv);            \
    lo = nlo; hi = nhi;                                 \
  }

__launch_bounds__(BT)
__global__ void fractal10(const float* __restrict__ x,
                          const int* __restrict__ dpt,
                          float* __restrict__ out, int n,
                          const float* __restrict__ ws) {
  if (dpt[0] != 10) return;
  __shared__ float sT[64];
  __shared__ __align__(16) float sbuf[64 * 32];  // 8KB: c(f16) then P(f32), per point 128B
  const int l = threadIdx.x;
  const int gid = blockIdx.x * BT + l;

  sT[l] = ws[l];
  const float4* fb = (const float4*)(ws + 4096);
  union f4h8 { float4 f; half8 h; };
  f4h8 A00, A01, A10, A11;
  A00.f = fb[0 * 64 + l];   // rt0 ks0
  A01.f = fb[1 * 64 + l];   // rt0 ks1
  A10.f = fb[2 * 64 + l];   // rt1 ks0
  A11.f = fb[3 * 64 + l];   // rt1 ks1
  const float xv = (gid < n) ? x[gid] : 0.5f;
  __syncthreads();

  float c[64];
  float lo = 0.f, hi = 1.f, tt, uu;
  c[0] = 1.f;
  PSTEP(1) PSTEP(2) PSTEP(4) PSTEP(8) PSTEP(16) PSTEP(32)

  // pack c -> f16, write [point][chunk] with XOR-16B swizzle
  {
    char* cb = (char*)sbuf + l * 128;
#pragma unroll
    for (int q = 0; q < 8; ++q) {
      const int k0 = (q >> 2) * 32 + (q & 3) * 4;
      union { fp16x2 h2[4]; float4 f4; } u;
      u.h2[0] = __builtin_amdgcn_cvt_pkrtz(c[k0], c[k0 + 1]);
      u.h2[1] = __builtin_amdgcn_cvt_pkrtz(c[k0 + 2], c[k0 + 3]);
      u.h2[2] = __builtin_amdgcn_cvt_pkrtz(c[k0 + 16], c[k0 + 17]);
      u.h2[3] = __builtin_amdgcn_cvt_pkrtz(c[k0 + 18], c[k0 + 19]);
      *(float4*)(cb + ((q ^ (l & 7)) * 16)) = u.f4;
    }
  }
  __syncthreads();

  // read B fragments (transposed c)
  half8 bf[2][4];
  const int col = l & 15, g = l >> 4;
#pragma unroll
  for (int ct = 0; ct < 4; ++ct) {
    const int p = 16 * ct + col;
    const char* pb = (const char*)sbuf + p * 128;
#pragma unroll
    for (int ks = 0; ks < 2; ++ks) {
      const int q = ks * 4 + g;
      bf[ks][ct] = *(const half8*)(pb + ((q ^ (p & 7)) * 16));
    }
  }
  __syncthreads();

  // P[32 x 64pts] = Bt(32x64) x C(64x64)
  f32x4 acc[2][4];
#pragma unroll
  for (int rt = 0; rt < 2; ++rt)
#pragma unroll
    for (int ct = 0; ct < 4; ++ct) acc[rt][ct] = f32x4{0.f, 0.f, 0.f, 0.f};
#pragma unroll
  for (int ct = 0; ct < 4; ++ct) {
    acc[0][ct] = __builtin_amdgcn_mfma_f32_16x16x32_f16(A00.h, bf[0][ct], acc[0][ct], 0, 0, 0);
    acc[0][ct] = __builtin_amdgcn_mfma_f32_16x16x32_f16(A01.h, bf[1][ct], acc[0][ct], 0, 0, 0);
    acc[1][ct] = __builtin_amdgcn_mfma_f32_16x16x32_f16(A10.h, bf[0][ct], acc[1][ct], 0, 0, 0);
    acc[1][ct] = __builtin_amdgcn_mfma_f32_16x16x32_f16(A11.h, bf[1][ct], acc[1][ct], 0, 0, 0);
  }

  // scatter P back: D layout col=lane&15, row=(lane>>4)*4+reg (m89-verified)
#pragma unroll
  for (int rt = 0; rt < 2; ++rt)
#pragma unroll
    for (int ct = 0; ct < 4; ++ct) {
      const int p = 16 * ct + col;
      const int rb = rt * 4 + g;
      *(f32x4*)((char*)sbuf + p * 128 + ((rb ^ (p & 7)) * 16)) = acc[rt][ct];
    }
  __syncthreads();
  float4 P[8];
#pragma unroll
  for (int j = 0; j < 8; ++j)
    P[j] = *(const float4*)((const char*)sbuf + l * 128 + ((j ^ (l & 7)) * 16));

  // sequential tail on P: rows 0 | 1..2 | 3..6 | 7..14 | 15..30
  SIGSTEP(P[0].x);
  const float w20 = uu, w21 = tt;
  SIGSTEP(fmaf(w20, P[0].y, w21 * P[0].z));
  float W4[4] = {w20 * uu, w20 * tt, w21 * uu, w21 * tt};
  SIGSTEP(fmaf(W4[0], P[0].w, fmaf(W4[1], P[1].x, fmaf(W4[2], P[1].y, W4[3] * P[1].z))));
  float W8[8];
#pragma unroll
  for (int s = 3; s >= 0; --s) { W8[2 * s + 1] = W4[s] * tt; W8[2 * s] = W4[s] * uu; }
  {
    float d0 = fmaf(W8[0], P[1].w, W8[1] * P[2].x);
    float d1 = fmaf(W8[2], P[2].y, W8[3] * P[2].z);
    float d2 = fmaf(W8[4], P[2].w, W8[5] * P[3].x);
    float d3 = fmaf(W8[6], P[3].y, W8[7] * P[3].z);
    SIGSTEP((d0 + d1) + (d2 + d3));
  }
  float W16[16];
#pragma unroll
  for (int s = 7; s >= 0; --s) { W16[2 * s + 1] = W8[s] * tt; W16[2 * s] = W8[s] * uu; }
  float outv;
  {
    float d0 = fmaf(W16[0], P[3].w, W16[1] * P[4].x);
    d0 = fmaf(W16[2], P[4].y, d0); d0 = fmaf(W16[3], P[4].z, d0);
    float d1 = fmaf(W16[4], P[4].w, W16[5] * P[5].x);
    d1 = fmaf(W16[6], P[5].y, d1); d1 = fmaf(W16[7], P[5].z, d1);
    float d2 = fmaf(W16[8], P[5].w, W16[9] * P[6].x);
    d2 = fmaf(W16[10], P[6].y, d2); d2 = fmaf(W16[11], P[6].z, d2);
    float d3 = fmaf(W16[12], P[6].w, W16[13] * P[7].x);
    d3 = fmaf(W16[14], P[7].y, d3); d3 = fmaf(W16[15], P[7].z, d3);
    outv = (d0 + d1) + (d2 + d3);
  }
  if (gid < n) out[gid] = outv;
}

// Generic-depth fallback (never taken when depth==10; correctness only).
// LDS-backed [node][tid] state, column-per-thread => no scratch, no barriers.
__launch_bounds__(64)
__global__ void fractal_generic(const float* __restrict__ x,
                                const int* __restrict__ dpt,
                                float* __restrict__ out, int n,
                                const float* __restrict__ ws) {
  const int depth = dpt[0];
  if (depth == 10) return;
  __shared__ float w[2][M][64];  // 64KB
  const int t = threadIdx.x;
  const float* sp = ws + 3072;
  const float* vals = ws + 3200;
  const int* li = (const int*)ws + 3328;
  const int* ri = (const int*)ws + 3456;
  for (int gid = blockIdx.x * 64 + t; gid < n; gid += gridDim.x * 64) {
    const float xv = x[gid];
    for (int j = 0; j < M; ++j) w[0][j][t] = 0.f;
    w[0][0][t] = 1.f;
    float lo = 0.f, hi = 1.f;
    int cb = 0;
    for (int k = 0; k < depth; ++k) {
      float dot = 0.f;
      for (int j = 0; j < M; ++j) dot += w[cb][j][t] * sp[j];
      const float sv = lo + dot * (hi - lo);
      const float tt = 1.f / (1.f + __expf((sv - xv) * 10.f));
      const float uu = 1.f - tt;
      for (int j = 0; j < M; ++j) w[cb ^ 1][j][t] = 0.f;
      for (int j = 0; j < M; ++j) {
        const float v = w[cb][j][t];
        w[cb ^ 1][li[j]][t] += uu * v;
        w[cb ^ 1][ri[j]][t] += tt * v;
      }
      const float nlo = uu * lo + tt * sv;
      const float nhi = uu * sv + tt * hi;
      lo = nlo; hi = nhi;
      cb ^= 1;
    }
    float acc = 0.f;
    for (int j = 0; j < M; ++j) acc += w[cb][j][t] * vals[j];
    out[gid] = acc;
  }
}

extern "C" void kernel_launch(void* const* d_in, const int* in_sizes, int n_in,
                              void* d_out, int out_size, void* d_ws, size_t ws_size,
                              hipStream_t stream) {
  const float* x   = (const float*)d_in[0];
  const float* spp = (const float*)d_in[1];
  const float* vp  = (const float*)d_in[2];
  const float* Lm  = (const float*)d_in[3];
  const float* Rm  = (const float*)d_in[4];
  const int* dpt   = (const int*)d_in[5];
  float* out = (float*)d_out;
  float* ws = (float*)d_ws;
  const int n = in_sizes[0];

  hipLaunchKernelGGL(setup_kernel, dim3(1), dim3(256), 0, stream, spp, vp, Lm, Rm, ws);
  const int blocks = (n + BT - 1) / BT;
  hipLaunchKernelGGL(fractal10, dim3(blocks), dim3(BT), 0, stream,
                     x, dpt, out, n, (const float*)ws);
  hipLaunchKernelGGL(fractal_generic, dim3(128), dim3(64), 0, stream, x, dpt, out, n,
                     (const float*)ws);
}